// Round 2
// baseline (858.924 us; speedup 1.0000x reference)
//
#include <hip/hip_runtime.h>

// Problem constants
#define NB   64
#define NR   50
#define LTOK 15
#define DIM  1024      // D (pooling dim), output per-half width
#define FEAT 4096      // F (K of the GEMM)
#define MTOT (NB*NR)   // 3200 rows
#define OSTRIDE (2*DIM)

// ---------------------------------------------------------------------------
// Kernel 1: segment mean over phrase tokens.
// phrases [B,R,L,D] fp32 (already zero-padded past length), lengths [B,R] i32
// out[b,r, D + d] = sum_l phrases[b,r,l,d] / len
// One block per (b,r); 256 threads x float4 covers D=1024.
// ---------------------------------------------------------------------------
__global__ __launch_bounds__(256) void mean_pool_kernel(
    const float* __restrict__ phrases,
    const int*   __restrict__ lengths,
    float*       __restrict__ out)
{
    const int br = blockIdx.x;            // 0..3199
    const int d4 = threadIdx.x;           // float4 index, 0..255
    const float4* p = reinterpret_cast<const float4*>(
        phrases + (size_t)br * LTOK * DIM) + d4;

    float4 acc = make_float4(0.f, 0.f, 0.f, 0.f);
    #pragma unroll
    for (int l = 0; l < LTOK; ++l) {
        float4 v = p[(size_t)l * (DIM / 4)];
        acc.x += v.x; acc.y += v.y; acc.z += v.z; acc.w += v.w;
    }
    const float inv = 1.0f / (float)lengths[br];
    acc.x *= inv; acc.y *= inv; acc.z *= inv; acc.w *= inv;

    reinterpret_cast<float4*>(out + (size_t)br * OSTRIDE + DIM)[d4] = acc;
}

// ---------------------------------------------------------------------------
// Kernel 2: vis = relu(features @ W^T + b), written to out[:, 0:D].
// A = features [M,K] row-major, Bw = W [N,K] row-major (both K-contiguous).
// fp32 VALU GEMM: 64x64 block tile, BK=32, 256 threads, 4x4 micro-tile.
// LDS tiles stored k-major (As[k][m], Bs[k][n]) so the inner loop does two
// ds_read_b128 + 16 v_fmac per k.
// Register prefetch of next global tile overlaps HBM latency with compute.
// ---------------------------------------------------------------------------
#define BM 64
#define BN 64
#define BK 32

__global__ __launch_bounds__(256) void gemm_relu_kernel(
    const float* __restrict__ A,     // [MTOT, FEAT]
    const float* __restrict__ Bw,    // [DIM,  FEAT]
    const float* __restrict__ bias,  // [DIM]
    float*       __restrict__ out)   // [MTOT, OSTRIDE]
{
    __shared__ float As[BK][BM];
    __shared__ float Bs[BK][BN];

    const int tid = threadIdx.x;
    const int m0 = blockIdx.y * BM;
    const int n0 = blockIdx.x * BN;

    // Staging: each thread loads rows (lr, lr+32), 4 consecutive k at lk.
    const int lr = tid >> 3;             // 0..31
    const int lk = (tid & 7) * 4;        // 0,4,...,28

    const float* Aptr = A  + (size_t)(m0 + lr) * FEAT + lk;
    const float* Bptr = Bw + (size_t)(n0 + lr) * FEAT + lk;

    // Micro-tile coordinates: 16x16 thread grid, 4x4 outputs each.
    const int tm0 = (tid >> 4) * 4;      // 0..60
    const int tn0 = (tid & 15) * 4;      // 0..60

    float acc[4][4] = {};

    // Prologue: load tile kt=0 into registers.
    float4 a0 = *reinterpret_cast<const float4*>(Aptr);
    float4 a1 = *reinterpret_cast<const float4*>(Aptr + (size_t)32 * FEAT);
    float4 b0 = *reinterpret_cast<const float4*>(Bptr);
    float4 b1 = *reinterpret_cast<const float4*>(Bptr + (size_t)32 * FEAT);

    const int NK = FEAT / BK;            // 128
    for (int kt = 0; kt < NK; ++kt) {
        // Registers -> LDS (transposed to k-major).
        As[lk + 0][lr]      = a0.x; As[lk + 1][lr]      = a0.y;
        As[lk + 2][lr]      = a0.z; As[lk + 3][lr]      = a0.w;
        As[lk + 0][lr + 32] = a1.x; As[lk + 1][lr + 32] = a1.y;
        As[lk + 2][lr + 32] = a1.z; As[lk + 3][lr + 32] = a1.w;
        Bs[lk + 0][lr]      = b0.x; Bs[lk + 1][lr]      = b0.y;
        Bs[lk + 2][lr]      = b0.z; Bs[lk + 3][lr]      = b0.w;
        Bs[lk + 0][lr + 32] = b1.x; Bs[lk + 1][lr + 32] = b1.y;
        Bs[lk + 2][lr + 32] = b1.z; Bs[lk + 3][lr + 32] = b1.w;
        __syncthreads();

        // Prefetch next tile into registers (overlaps with compute below).
        if (kt + 1 < NK) {
            const float* Ap = Aptr + (size_t)(kt + 1) * BK;
            const float* Bp = Bptr + (size_t)(kt + 1) * BK;
            a0 = *reinterpret_cast<const float4*>(Ap);
            a1 = *reinterpret_cast<const float4*>(Ap + (size_t)32 * FEAT);
            b0 = *reinterpret_cast<const float4*>(Bp);
            b1 = *reinterpret_cast<const float4*>(Bp + (size_t)32 * FEAT);
        }

        #pragma unroll
        for (int k = 0; k < BK; ++k) {
            const float4 av = *reinterpret_cast<const float4*>(&As[k][tm0]);
            const float4 bv = *reinterpret_cast<const float4*>(&Bs[k][tn0]);
            acc[0][0] += av.x * bv.x; acc[0][1] += av.x * bv.y;
            acc[0][2] += av.x * bv.z; acc[0][3] += av.x * bv.w;
            acc[1][0] += av.y * bv.x; acc[1][1] += av.y * bv.y;
            acc[1][2] += av.y * bv.z; acc[1][3] += av.y * bv.w;
            acc[2][0] += av.z * bv.x; acc[2][1] += av.z * bv.y;
            acc[2][2] += av.z * bv.z; acc[2][3] += av.z * bv.w;
            acc[3][0] += av.w * bv.x; acc[3][1] += av.w * bv.y;
            acc[3][2] += av.w * bv.z; acc[3][3] += av.w * bv.w;
        }
        __syncthreads();
    }

    // Epilogue: bias + relu, vectorized float4 store into left half of out.
    const float4 bv = *reinterpret_cast<const float4*>(&bias[n0 + tn0]);
    #pragma unroll
    for (int i = 0; i < 4; ++i) {
        float4 v;
        v.x = acc[i][0] + bv.x; v.y = acc[i][1] + bv.y;
        v.z = acc[i][2] + bv.z; v.w = acc[i][3] + bv.w;
        v.x = fmaxf(v.x, 0.f); v.y = fmaxf(v.y, 0.f);
        v.z = fmaxf(v.z, 0.f); v.w = fmaxf(v.w, 0.f);
        *reinterpret_cast<float4*>(
            out + (size_t)(m0 + tm0 + i) * OSTRIDE + (n0 + tn0)) = v;
    }
}

// ---------------------------------------------------------------------------
// Inputs (setup_inputs dict order):
//   d_in[0] features       [B,R,F]   fp32
//   d_in[1] phrases        [B,R,L,D] fp32
//   d_in[2] W              [D,F]     fp32
//   d_in[3] b              [D]       fp32
//   d_in[4] phrase_lengths [B,R]     int32
// Output: [B,R,2D] fp32 — vis in cols [0,D), mean_phrase in cols [D,2D).
// ---------------------------------------------------------------------------
extern "C" void kernel_launch(void* const* d_in, const int* in_sizes, int n_in,
                              void* d_out, int out_size, void* d_ws, size_t ws_size,
                              hipStream_t stream) {
    const float* features = (const float*)d_in[0];
    const float* phrases  = (const float*)d_in[1];
    const float* W        = (const float*)d_in[2];
    const float* bias     = (const float*)d_in[3];
    const int*   lengths  = (const int*)d_in[4];
    float* out = (float*)d_out;

    mean_pool_kernel<<<dim3(MTOT), dim3(256), 0, stream>>>(phrases, lengths, out);

    gemm_relu_kernel<<<dim3(DIM / BN, MTOT / BM), dim3(256), 0, stream>>>(
        features, W, bias, out);
}

// Round 3
// 513.107 us; speedup vs baseline: 1.6740x; 1.6740x over previous
//
#include <hip/hip_runtime.h>

// Problem constants
#define NB   64
#define NR   50
#define LTOK 15
#define DIM  1024      // D (pooling dim), output per-half width
#define FEAT 4096      // F (K of the GEMM)
#define MTOT (NB*NR)   // 3200 rows
#define OSTRIDE (2*DIM)

typedef __attribute__((ext_vector_type(8))) short bf16x8;  // 8 bf16 = 4 VGPRs
typedef __attribute__((ext_vector_type(4))) float f32x4;   // MFMA C/D frag

// ---------------------------------------------------------------------------
// Kernel 1: segment mean over phrase tokens (unchanged from round 2).
// out[b,r, D + d] = sum_l phrases[b,r,l,d] / len
// ---------------------------------------------------------------------------
__global__ __launch_bounds__(256) void mean_pool_kernel(
    const float* __restrict__ phrases,
    const int*   __restrict__ lengths,
    float*       __restrict__ out)
{
    const int br = blockIdx.x;            // 0..3199
    const int d4 = threadIdx.x;           // float4 index, 0..255
    const float4* p = reinterpret_cast<const float4*>(
        phrases + (size_t)br * LTOK * DIM) + d4;

    float4 acc = make_float4(0.f, 0.f, 0.f, 0.f);
    #pragma unroll
    for (int l = 0; l < LTOK; ++l) {
        float4 v = p[(size_t)l * (DIM / 4)];
        acc.x += v.x; acc.y += v.y; acc.z += v.z; acc.w += v.w;
    }
    const float inv = 1.0f / (float)lengths[br];
    acc.x *= inv; acc.y *= inv; acc.z *= inv; acc.w *= inv;

    reinterpret_cast<float4*>(out + (size_t)br * OSTRIDE + DIM)[d4] = acc;
}

// ---------------------------------------------------------------------------
// Kernel 2: vis = relu(features @ W^T + b) via split-bf16 MFMA.
// a = a_hi + a_lo (two bf16), product a*b ~= ah*bh + ah*bl + al*bh (fp32 acc),
// dropped al*bl term ~2^-16 relative -> fp32-grade accuracy.
//
// 128x128 tile, BK=32, 4 waves (2x2), wave tile 64x64 = 4x4 frags of
// v_mfma_f32_16x16x32_bf16. Reg-staged global->convert->LDS (conversion
// requires the register round-trip). LDS pitch 40 ushorts (80 B) to break
// bank conflicts on ds_read_b128 frag loads (~2-way residual = free).
// Register prefetch of next k-tile overlaps global latency with MFMA.
// ---------------------------------------------------------------------------
#define BM 128
#define BN 128
#define BK 32
#define LDSP 40   // padded row pitch in ushorts (80 B, 16B-aligned)

__device__ __forceinline__ unsigned short bf16_rne(float f) {
    unsigned int u = __builtin_bit_cast(unsigned int, f);
    unsigned int r = (u + 0x7fffu + ((u >> 16) & 1u)) >> 16;   // round-to-nearest-even
    return (unsigned short)r;
}
__device__ __forceinline__ float bf16_to_f(unsigned short h) {
    return __builtin_bit_cast(float, (unsigned int)h << 16);
}

__device__ __forceinline__ void split4(const float4 v, ushort4& h, ushort4& l) {
    h.x = bf16_rne(v.x); l.x = bf16_rne(v.x - bf16_to_f(h.x));
    h.y = bf16_rne(v.y); l.y = bf16_rne(v.y - bf16_to_f(h.y));
    h.z = bf16_rne(v.z); l.z = bf16_rne(v.z - bf16_to_f(h.z));
    h.w = bf16_rne(v.w); l.w = bf16_rne(v.w - bf16_to_f(h.w));
}

__global__ __launch_bounds__(256, 1) void gemm_relu_mfma(
    const float* __restrict__ A,     // [MTOT, FEAT] row-major (k contiguous)
    const float* __restrict__ Bw,    // [DIM,  FEAT] row-major (k contiguous)
    const float* __restrict__ bias,  // [DIM]
    float*       __restrict__ out)   // [MTOT, OSTRIDE], writes cols [0,DIM)
{
    __shared__ __align__(16) unsigned short Ah[BM][LDSP];
    __shared__ __align__(16) unsigned short Al[BM][LDSP];
    __shared__ __align__(16) unsigned short Bh[BN][LDSP];
    __shared__ __align__(16) unsigned short Bl[BN][LDSP];

    const int tid = threadIdx.x;
    const int m0  = blockIdx.y * BM;   // M-tile
    const int n0  = blockIdx.x * BN;   // N-tile (varies fastest -> XCD = n-col)

    // --- staging map: thread t loads rows {t>>3 + 32p}, float4 slot t&7 ---
    const int srow = tid >> 3;           // 0..31
    const int scol = (tid & 7) * 4;      // float index within BK (0,4,..,28)

    const float* Aptr = A  + (size_t)(m0 + srow) * FEAT + scol;
    const float* Bptr = Bw + (size_t)(n0 + srow) * FEAT + scol;

    // --- wave / fragment map ---
    const int lane = tid & 63;
    const int wr   = ((tid >> 6) >> 1) * 64;   // wave M offset (0 or 64)
    const int wc   = ((tid >> 6) & 1) * 64;    // wave N offset (0 or 64)
    const int fr   = lane & 15;                // row (A) / col (B) in fragment
    const int fk   = (lane >> 4) * 8;          // k offset in fragment

    f32x4 acc[4][4] = {};                      // 4x4 frags of 16x16

    // Prologue: prefetch k-tile 0 into registers.
    float4 pa[4], pb[4];
    #pragma unroll
    for (int p = 0; p < 4; ++p) {
        pa[p] = *reinterpret_cast<const float4*>(Aptr + (size_t)(p * 32) * FEAT);
        pb[p] = *reinterpret_cast<const float4*>(Bptr + (size_t)(p * 32) * FEAT);
    }

    const int NK = FEAT / BK;   // 128
    for (int kt = 0; kt < NK; ++kt) {
        __syncthreads();   // previous iteration's frag reads done before overwrite

        // Convert staged registers -> hi/lo bf16, write to LDS (b64 writes).
        #pragma unroll
        for (int p = 0; p < 4; ++p) {
            const int r = srow + p * 32;
            ushort4 h, l;
            split4(pa[p], h, l);
            *reinterpret_cast<ushort4*>(&Ah[r][scol]) = h;
            *reinterpret_cast<ushort4*>(&Al[r][scol]) = l;
            split4(pb[p], h, l);
            *reinterpret_cast<ushort4*>(&Bh[r][scol]) = h;
            *reinterpret_cast<ushort4*>(&Bl[r][scol]) = l;
        }
        __syncthreads();

        // Prefetch next k-tile (lands while MFMAs below execute).
        if (kt + 1 < NK) {
            const float* An = Aptr + (size_t)(kt + 1) * BK;
            const float* Bn = Bptr + (size_t)(kt + 1) * BK;
            #pragma unroll
            for (int p = 0; p < 4; ++p) {
                pa[p] = *reinterpret_cast<const float4*>(An + (size_t)(p * 32) * FEAT);
                pb[p] = *reinterpret_cast<const float4*>(Bn + (size_t)(p * 32) * FEAT);
            }
        }

        // Fragment loads: 16 x ds_read_b128 per thread.
        bf16x8 fah[4], fal[4], fbh[4], fbl[4];
        #pragma unroll
        for (int m = 0; m < 4; ++m) {
            fah[m] = *reinterpret_cast<const bf16x8*>(&Ah[wr + m * 16 + fr][fk]);
            fal[m] = *reinterpret_cast<const bf16x8*>(&Al[wr + m * 16 + fr][fk]);
        }
        #pragma unroll
        for (int n = 0; n < 4; ++n) {
            fbh[n] = *reinterpret_cast<const bf16x8*>(&Bh[wc + n * 16 + fr][fk]);
            fbl[n] = *reinterpret_cast<const bf16x8*>(&Bl[wc + n * 16 + fr][fk]);
        }

        // 48 MFMAs: hh + hl + lh accumulated into the same acc (16 indep chains).
        #pragma unroll
        for (int m = 0; m < 4; ++m) {
            #pragma unroll
            for (int n = 0; n < 4; ++n) {
                acc[m][n] = __builtin_amdgcn_mfma_f32_16x16x32_bf16(
                    fah[m], fbl[n], acc[m][n], 0, 0, 0);
                acc[m][n] = __builtin_amdgcn_mfma_f32_16x16x32_bf16(
                    fal[m], fbh[n], acc[m][n], 0, 0, 0);
                acc[m][n] = __builtin_amdgcn_mfma_f32_16x16x32_bf16(
                    fah[m], fbh[n], acc[m][n], 0, 0, 0);
            }
        }
    }

    // Epilogue: C/D layout col = lane&15, row = (lane>>4)*4 + reg  [m89].
    const int orow0 = m0 + wr + (lane >> 4) * 4;
    const int ocol0 = n0 + wc + fr;
    #pragma unroll
    for (int n = 0; n < 4; ++n) {
        const float bv = bias[ocol0 + n * 16];
        #pragma unroll
        for (int m = 0; m < 4; ++m) {
            #pragma unroll
            for (int r = 0; r < 4; ++r) {
                float v = acc[m][n][r] + bv;
                v = fmaxf(v, 0.f);
                out[(size_t)(orow0 + m * 16 + r) * OSTRIDE + (ocol0 + n * 16)] = v;
            }
        }
    }
}

// ---------------------------------------------------------------------------
// Inputs (setup_inputs dict order):
//   d_in[0] features [B,R,F] fp32;  d_in[1] phrases [B,R,L,D] fp32
//   d_in[2] W [D,F] fp32;  d_in[3] b [D] fp32;  d_in[4] lengths [B,R] i32
// Output: [B,R,2D] fp32 — vis in cols [0,D), mean_phrase in cols [D,2D).
// ---------------------------------------------------------------------------
extern "C" void kernel_launch(void* const* d_in, const int* in_sizes, int n_in,
                              void* d_out, int out_size, void* d_ws, size_t ws_size,
                              hipStream_t stream) {
    const float* features = (const float*)d_in[0];
    const float* phrases  = (const float*)d_in[1];
    const float* W        = (const float*)d_in[2];
    const float* bias     = (const float*)d_in[3];
    const int*   lengths  = (const int*)d_in[4];
    float* out = (float*)d_out;

    mean_pool_kernel<<<dim3(MTOT), dim3(256), 0, stream>>>(phrases, lengths, out);

    // grid.x = N-tiles (8): round-robin wg->XCD pins each N-column to one XCD,
    // keeping its W-panel (2 MB) L2-resident across all 25 M-blocks.
    gemm_relu_mfma<<<dim3(DIM / BN, MTOT / BM), dim3(256), 0, stream>>>(
        features, W, bias, out);
}

// Round 5
// 428.806 us; speedup vs baseline: 2.0031x; 1.1966x over previous
//
#include <hip/hip_runtime.h>

// Problem constants
#define NB   64
#define NR   50
#define LTOK 15
#define DIM  1024      // D (pooling dim), output per-half width
#define FEAT 4096      // F (K of the GEMM)
#define MTOT (NB*NR)   // 3200 rows
#define OSTRIDE (2*DIM)

typedef __attribute__((ext_vector_type(8))) short bf16x8;  // 8 bf16 = 4 VGPRs
typedef __attribute__((ext_vector_type(4))) float f32x4;   // MFMA C/D frag

// ---- workspace layout (bytes) ----
#define WS_AH 0ull
#define WS_AL 26214400ull            // 3200*4096*2
#define WS_BH 52428800ull
#define WS_BL 60817408ull            // + 1024*4096*2
#define WS_PB 69206016ull            // partials: 4 x 3200 x 1024 f32
#define WS_NEED 121634816ull

#define NSPLIT 4
#define KSTEPS_TOTAL 384             // 3 phases x 128 k-steps of 32
#define KS_PER_SPLIT 96
#define GEMM_BLOCKS 800              // 8 n-tiles x 25 m-tiles x 4 k-splits

// global_load_lds, 16B/lane; LDS dest = wave-uniform base + lane*16 (m97).
// NOTE: LDS side is a POINTER addrspacecast (generic->as3), not inttoptr —
// the compiler folds it to the LDS byte offset. Global side cast drops const.
#define GLOAD16(gsrc, ldst)                                                   \
    __builtin_amdgcn_global_load_lds(                                         \
        (__attribute__((address_space(1))) void*)(gsrc),                      \
        (__attribute__((address_space(3))) void*)(ldst), 16, 0, 0)

// ---------------------------------------------------------------------------
// Kernel 1: one-time exact hi/lo bf16 split of A (features) and W into ws.
// Truncation split: h = top16(x); l = top16(x - h).  x = h + l + O(2^-16 x).
// ---------------------------------------------------------------------------
__device__ __forceinline__ void split_trunc(float x, unsigned short& h, unsigned short& l) {
    unsigned int u = __builtin_bit_cast(unsigned int, x);
    h = (unsigned short)(u >> 16);
    float r = x - __builtin_bit_cast(float, u & 0xffff0000u);
    l = (unsigned short)(__builtin_bit_cast(unsigned int, r) >> 16);
}

__global__ __launch_bounds__(256) void split_kernel(
    const float* __restrict__ A, const float* __restrict__ W,
    unsigned short* __restrict__ Ah, unsigned short* __restrict__ Al,
    unsigned short* __restrict__ Bh, unsigned short* __restrict__ Bl)
{
    const int NA4 = MTOT * FEAT / 4;   // 3,276,800 float4s of A
    const int NW4 = DIM * FEAT / 4;    // 1,048,576 float4s of W
    for (int i = blockIdx.x * 256 + threadIdx.x; i < NA4 + NW4;
         i += gridDim.x * 256) {
        const bool isA = i < NA4;
        const int  j   = isA ? i : i - NA4;
        const float4 v = isA ? reinterpret_cast<const float4*>(A)[j]
                             : reinterpret_cast<const float4*>(W)[j];
        ushort4 h, l;
        split_trunc(v.x, h.x, l.x); split_trunc(v.y, h.y, l.y);
        split_trunc(v.z, h.z, l.z); split_trunc(v.w, h.w, l.w);
        if (isA) {
            reinterpret_cast<ushort4*>(Ah)[j] = h;
            reinterpret_cast<ushort4*>(Al)[j] = l;
        } else {
            reinterpret_cast<ushort4*>(Bh)[j] = h;
            reinterpret_cast<ushort4*>(Bl)[j] = l;
        }
    }
}

// ---------------------------------------------------------------------------
// Kernel 2 (fused): blocks [0,800) = bf16 MFMA GEMM partials over K'=12288
// (phases: Ah.Bh | Al.Bh | Ah.Bl), split-K=4; blocks [800,4000) = mean-pool.
//
// GEMM block: 128x128 tile, BK=32, 256 thr / 4 waves, wave-tile 64x64
// (4x4 frags of mfma_f32_16x16x32_bf16 = 16 MFMA : 8 ds_read_b128 per step).
// T3 2-phase: stage next k-step via global_load_lds BEFORE compute; ONE
// barrier per step (its implicit vmcnt(0) lands after ~200cyc of compute).
// LDS linear [128][32] bf16 (gload_lds requires it) -> 8-way frag-read
// conflict accepted this round (T2 swizzle is the next lever).
// ---------------------------------------------------------------------------
__global__ __launch_bounds__(256, 3) void gemm_mp_kernel(
    const unsigned short* __restrict__ Ah, const unsigned short* __restrict__ Al,
    const unsigned short* __restrict__ Bh, const unsigned short* __restrict__ Bl,
    const float* __restrict__ phrases, const int* __restrict__ lengths,
    float* __restrict__ pbuf, float* __restrict__ out)
{
    if (blockIdx.x >= GEMM_BLOCKS) {
        // ---------------- mean-pool path (1 row per block) ----------------
        const int br = blockIdx.x - GEMM_BLOCKS;          // 0..3199
        const int d4 = threadIdx.x;                       // 0..255
        const float4* p = reinterpret_cast<const float4*>(
            phrases + (size_t)br * LTOK * DIM) + d4;
        float4 acc = make_float4(0.f, 0.f, 0.f, 0.f);
        #pragma unroll
        for (int l = 0; l < LTOK; ++l) {
            float4 v = p[(size_t)l * (DIM / 4)];
            acc.x += v.x; acc.y += v.y; acc.z += v.z; acc.w += v.w;
        }
        const float inv = 1.0f / (float)lengths[br];
        acc.x *= inv; acc.y *= inv; acc.z *= inv; acc.w *= inv;
        reinterpret_cast<float4*>(out + (size_t)br * OSTRIDE + DIM)[d4] = acc;
        return;
    }

    // ------------------------------ GEMM path ------------------------------
    __shared__ unsigned short At[2][128][32];
    __shared__ unsigned short Bt[2][128][32];

    const int bid  = blockIdx.x;
    const int nt   = bid & 7;            // XCD-aligned: XCD x always sees n-tile x
    const int rest = bid >> 3;
    const int mt   = rest % 25;
    const int q    = rest / 25;          // k-split 0..3

    const int tid  = threadIdx.x;
    const int lane = tid & 63;
    const int w    = tid >> 6;
    const int wr   = (w >> 1) * 64;      // wave-tile M offset
    const int wc   = (w & 1) * 64;       // wave-tile N offset
    const int fr   = lane & 15;
    const int fk   = (lane >> 4) * 8;

    // staging geometry: wave w fills 16-row chunks c0 and c0+1 of both tiles
    const int c0    = w * 2;
    const int srow  = lane >> 2;         // 0..15 within chunk
    const int skoff = (lane & 3) * 8;    // bf16 elems within the 32-wide k-slice
    const unsigned aoff0 = (unsigned)(mt * 128 + 16 * c0      + srow) * FEAT + skoff;
    const unsigned aoff1 = (unsigned)(mt * 128 + 16 * (c0+1)  + srow) * FEAT + skoff;
    const unsigned boff0 = (unsigned)(nt * 128 + 16 * c0      + srow) * FEAT + skoff;
    const unsigned boff1 = (unsigned)(nt * 128 + 16 * (c0+1)  + srow) * FEAT + skoff;

    auto stage = [&](int buf, int s) {
        // phase select: [0,128)=Ah.Bh  [128,256)=Al.Bh  [256,384)=Ah.Bl
        const unsigned short* aS = (s < 128) ? Ah : (s < 256 ? Al : Ah);
        const unsigned short* bS = (s < 256) ? Bh : Bl;
        const unsigned kk = (unsigned)(s & 127) * 32;
        GLOAD16(aS + aoff0 + kk, &At[buf][16 * c0][0]);
        GLOAD16(aS + aoff1 + kk, &At[buf][16 * c0 + 16][0]);
        GLOAD16(bS + boff0 + kk, &Bt[buf][16 * c0][0]);
        GLOAD16(bS + boff1 + kk, &Bt[buf][16 * c0 + 16][0]);
    };

    f32x4 acc[4][4] = {};
    const int s0 = q * KS_PER_SPLIT;

    stage(0, s0);
    __syncthreads();   // drains vmcnt(0): tile 0 resident

    for (int i = 0; i < KS_PER_SPLIT; ++i) {
        const int buf = i & 1;
        if (i + 1 < KS_PER_SPLIT) stage(buf ^ 1, s0 + i + 1);  // issue-early

        bf16x8 a[4], b[4];
        #pragma unroll
        for (int m = 0; m < 4; ++m)
            a[m] = *reinterpret_cast<const bf16x8*>(&At[buf][wr + m * 16 + fr][fk]);
        #pragma unroll
        for (int n = 0; n < 4; ++n)
            b[n] = *reinterpret_cast<const bf16x8*>(&Bt[buf][wc + n * 16 + fr][fk]);

        #pragma unroll
        for (int m = 0; m < 4; ++m)
            #pragma unroll
            for (int n = 0; n < 4; ++n)
                acc[m][n] = __builtin_amdgcn_mfma_f32_16x16x32_bf16(
                    a[m], b[n], acc[m][n], 0, 0, 0);

        __syncthreads();   // one barrier/step: next-tile vmcnt + read/write fence
    }

    // partial store: pbuf[q][row][col]  (C/D layout: col=lane&15, row=(lane>>4)*4+r)
    const int prow0 = mt * 128 + wr + (lane >> 4) * 4;
    const int pcol0 = nt * 128 + wc + fr;
    float* pq = pbuf + (size_t)q * MTOT * DIM;
    #pragma unroll
    for (int m = 0; m < 4; ++m)
        #pragma unroll
        for (int n = 0; n < 4; ++n)
            #pragma unroll
            for (int r = 0; r < 4; ++r)
                pq[(size_t)(prow0 + m * 16 + r) * DIM + (pcol0 + n * 16)] =
                    acc[m][n][r];
}

// ---------------------------------------------------------------------------
// Kernel 3: vis = relu(sum_q pbuf[q] + bias) -> out[:, 0:D). One row/block.
// ---------------------------------------------------------------------------
__global__ __launch_bounds__(256) void epi_kernel(
    const float* __restrict__ pbuf, const float* __restrict__ bias,
    float* __restrict__ out)
{
    const int r = blockIdx.x;        // 0..3199
    const int j = threadIdx.x;       // float4 col, 0..255
    const size_t qs = (size_t)MTOT * (DIM / 4);
    const float4* p = reinterpret_cast<const float4*>(pbuf) + (size_t)r * (DIM / 4) + j;
    float4 s0 = p[0], s1 = p[qs], s2 = p[2 * qs], s3 = p[3 * qs];
    const float4 bv = reinterpret_cast<const float4*>(bias)[j];
    float4 v;
    v.x = fmaxf(s0.x + s1.x + s2.x + s3.x + bv.x, 0.f);
    v.y = fmaxf(s0.y + s1.y + s2.y + s3.y + bv.y, 0.f);
    v.z = fmaxf(s0.z + s1.z + s2.z + s3.z + bv.z, 0.f);
    v.w = fmaxf(s0.w + s1.w + s2.w + s3.w + bv.w, 0.f);
    reinterpret_cast<float4*>(out + (size_t)r * OSTRIDE)[j] = v;
}

// ===========================================================================
// FALLBACK path (ws too small): round-3 verified kernels, unchanged.
// ===========================================================================
__global__ __launch_bounds__(256) void mean_pool_kernel(
    const float* __restrict__ phrases, const int* __restrict__ lengths,
    float* __restrict__ out)
{
    const int br = blockIdx.x;
    const int d4 = threadIdx.x;
    const float4* p = reinterpret_cast<const float4*>(
        phrases + (size_t)br * LTOK * DIM) + d4;
    float4 acc = make_float4(0.f, 0.f, 0.f, 0.f);
    #pragma unroll
    for (int l = 0; l < LTOK; ++l) {
        float4 v = p[(size_t)l * (DIM / 4)];
        acc.x += v.x; acc.y += v.y; acc.z += v.z; acc.w += v.w;
    }
    const float inv = 1.0f / (float)lengths[br];
    acc.x *= inv; acc.y *= inv; acc.z *= inv; acc.w *= inv;
    reinterpret_cast<float4*>(out + (size_t)br * OSTRIDE + DIM)[d4] = acc;
}

#define BM 128
#define BN 128
#define BK 32
#define LDSP 40

__device__ __forceinline__ unsigned short bf16_rne(float f) {
    unsigned int u = __builtin_bit_cast(unsigned int, f);
    unsigned int r = (u + 0x7fffu + ((u >> 16) & 1u)) >> 16;
    return (unsigned short)r;
}
__device__ __forceinline__ float bf16_to_f(unsigned short h) {
    return __builtin_bit_cast(float, (unsigned int)h << 16);
}
__device__ __forceinline__ void split4(const float4 v, ushort4& h, ushort4& l) {
    h.x = bf16_rne(v.x); l.x = bf16_rne(v.x - bf16_to_f(h.x));
    h.y = bf16_rne(v.y); l.y = bf16_rne(v.y - bf16_to_f(h.y));
    h.z = bf16_rne(v.z); l.z = bf16_rne(v.z - bf16_to_f(h.z));
    h.w = bf16_rne(v.w); l.w = bf16_rne(v.w - bf16_to_f(h.w));
}

__global__ __launch_bounds__(256, 1) void gemm_relu_mfma(
    const float* __restrict__ A, const float* __restrict__ Bw,
    const float* __restrict__ bias, float* __restrict__ out)
{
    __shared__ __align__(16) unsigned short AhS[BM][LDSP];
    __shared__ __align__(16) unsigned short AlS[BM][LDSP];
    __shared__ __align__(16) unsigned short BhS[BN][LDSP];
    __shared__ __align__(16) unsigned short BlS[BN][LDSP];

    const int tid = threadIdx.x;
    const int m0  = blockIdx.y * BM;
    const int n0  = blockIdx.x * BN;
    const int srow = tid >> 3;
    const int scol = (tid & 7) * 4;
    const float* Aptr = A  + (size_t)(m0 + srow) * FEAT + scol;
    const float* Bptr = Bw + (size_t)(n0 + srow) * FEAT + scol;
    const int lane = tid & 63;
    const int wr   = ((tid >> 6) >> 1) * 64;
    const int wc   = ((tid >> 6) & 1) * 64;
    const int fr   = lane & 15;
    const int fk   = (lane >> 4) * 8;

    f32x4 acc[4][4] = {};
    float4 pa[4], pb[4];
    #pragma unroll
    for (int p = 0; p < 4; ++p) {
        pa[p] = *reinterpret_cast<const float4*>(Aptr + (size_t)(p * 32) * FEAT);
        pb[p] = *reinterpret_cast<const float4*>(Bptr + (size_t)(p * 32) * FEAT);
    }
    const int NK = FEAT / BK;
    for (int kt = 0; kt < NK; ++kt) {
        __syncthreads();
        #pragma unroll
        for (int p = 0; p < 4; ++p) {
            const int r = srow + p * 32;
            ushort4 h, l;
            split4(pa[p], h, l);
            *reinterpret_cast<ushort4*>(&AhS[r][scol]) = h;
            *reinterpret_cast<ushort4*>(&AlS[r][scol]) = l;
            split4(pb[p], h, l);
            *reinterpret_cast<ushort4*>(&BhS[r][scol]) = h;
            *reinterpret_cast<ushort4*>(&BlS[r][scol]) = l;
        }
        __syncthreads();
        if (kt + 1 < NK) {
            const float* An = Aptr + (size_t)(kt + 1) * BK;
            const float* Bn = Bptr + (size_t)(kt + 1) * BK;
            #pragma unroll
            for (int p = 0; p < 4; ++p) {
                pa[p] = *reinterpret_cast<const float4*>(An + (size_t)(p * 32) * FEAT);
                pb[p] = *reinterpret_cast<const float4*>(Bn + (size_t)(p * 32) * FEAT);
            }
        }
        bf16x8 fah[4], fal[4], fbh[4], fbl[4];
        #pragma unroll
        for (int m = 0; m < 4; ++m) {
            fah[m] = *reinterpret_cast<const bf16x8*>(&AhS[wr + m * 16 + fr][fk]);
            fal[m] = *reinterpret_cast<const bf16x8*>(&AlS[wr + m * 16 + fr][fk]);
        }
        #pragma unroll
        for (int n = 0; n < 4; ++n) {
            fbh[n] = *reinterpret_cast<const bf16x8*>(&BhS[wc + n * 16 + fr][fk]);
            fbl[n] = *reinterpret_cast<const bf16x8*>(&BlS[wc + n * 16 + fr][fk]);
        }
        #pragma unroll
        for (int m = 0; m < 4; ++m)
            #pragma unroll
            for (int n = 0; n < 4; ++n) {
                acc[m][n] = __builtin_amdgcn_mfma_f32_16x16x32_bf16(fah[m], fbl[n], acc[m][n], 0, 0, 0);
                acc[m][n] = __builtin_amdgcn_mfma_f32_16x16x32_bf16(fal[m], fbh[n], acc[m][n], 0, 0, 0);
                acc[m][n] = __builtin_amdgcn_mfma_f32_16x16x32_bf16(fah[m], fbh[n], acc[m][n], 0, 0, 0);
            }
    }
    const int orow0 = m0 + wr + (lane >> 4) * 4;
    const int ocol0 = n0 + wc + fr;
    #pragma unroll
    for (int n = 0; n < 4; ++n) {
        const float bv = bias[ocol0 + n * 16];
        #pragma unroll
        for (int m = 0; m < 4; ++m)
            #pragma unroll
            for (int r = 0; r < 4; ++r) {
                float v = acc[m][n][r] + bv;
                out[(size_t)(orow0 + m * 16 + r) * OSTRIDE + (ocol0 + n * 16)] =
                    fmaxf(v, 0.f);
            }
    }
}

// ---------------------------------------------------------------------------
// Inputs: d_in[0] features f32, [1] phrases f32, [2] W f32, [3] b f32,
//         [4] phrase_lengths i32.  Output [B,R,2D] f32.
// ---------------------------------------------------------------------------
extern "C" void kernel_launch(void* const* d_in, const int* in_sizes, int n_in,
                              void* d_out, int out_size, void* d_ws, size_t ws_size,
                              hipStream_t stream) {
    const float* features = (const float*)d_in[0];
    const float* phrases  = (const float*)d_in[1];
    const float* W        = (const float*)d_in[2];
    const float* bias     = (const float*)d_in[3];
    const int*   lengths  = (const int*)d_in[4];
    float* out = (float*)d_out;

    if (ws_size >= WS_NEED) {
        char* ws = (char*)d_ws;
        unsigned short* Ah = (unsigned short*)(ws + WS_AH);
        unsigned short* Al = (unsigned short*)(ws + WS_AL);
        unsigned short* Bh = (unsigned short*)(ws + WS_BH);
        unsigned short* Bl = (unsigned short*)(ws + WS_BL);
        float* pbuf = (float*)(ws + WS_PB);

        split_kernel<<<dim3(2048), dim3(256), 0, stream>>>(
            features, W, Ah, Al, Bh, Bl);
        gemm_mp_kernel<<<dim3(GEMM_BLOCKS + MTOT), dim3(256), 0, stream>>>(
            Ah, Al, Bh, Bl, phrases, lengths, pbuf, out);
        epi_kernel<<<dim3(MTOT), dim3(256), 0, stream>>>(pbuf, bias, out);
    } else {
        // ws too small: round-3 verified path
        mean_pool_kernel<<<dim3(MTOT), dim3(256), 0, stream>>>(phrases, lengths, out);
        gemm_relu_mfma<<<dim3(DIM / BN, MTOT / BM), dim3(256), 0, stream>>>(
            features, W, bias, out);
    }
}